// Round 6
// baseline (512.430 us; speedup 1.0000x reference)
//
#include <hip/hip_runtime.h>
#include <hip/hip_cooperative_groups.h>

// HaloAttention. B=2, H=W=128, C=128, NH=4, hd=32, WS=16, HS=8, WSH=32.
// R11: ledger shows non-halo time is a CONSTANT ~110us across R5-R10 despite
// kernel-internal changes (incl. -32MB traffic, -1 launch) => inter-dispatch
// overhead, not kernel execution. Collapse all 4 dispatches into ONE
// cooperative kernel with 3 grid syncs. Phase math identical to R9/R8
// (GEMMs re-tiled 128->64 rows for the 512-block grid; halo = R8 body
// verbatim). Fallback to the proven 4-launch path if coop launch fails.

namespace cg = cooperative_groups;

typedef unsigned short ushort_t;
typedef __attribute__((ext_vector_type(8))) short bf16x8;
typedef __attribute__((ext_vector_type(4))) float floatx4;

#define NHEADS 4
#define BTBL 2209          // 47*47 bias table rows
#define PK 64              // key stride (bf16) for P/Vt LDS rows (128B, aligned)
#define LOG2E 1.4426950408889634f
#define QSCALE (0.17677669529663687f * LOG2E)   // head_dim^-0.5 * log2(e)

__device__ __forceinline__ int reflect_idx(int p) {
    p = (p < 0) ? -p : p;
    p = (p > 127) ? 254 - p : p;
    return p;
}

// fp32 -> bf16 bits, RNE
__device__ __forceinline__ ushort_t f2b(float x) {
    unsigned u = __float_as_uint(x);
    return (ushort_t)((u + 0x7fffu + ((u >> 16) & 1u)) >> 16);
}

// ===========================================================================
// Fused cooperative kernel: 512 blocks x 256 threads, 2 blocks/CU.
// phase0 prep -> sync -> phase1 QKV gemm -> sync -> phase2 halo -> sync ->
// phase3 proj gemm.
// ===========================================================================
__global__ __launch_bounds__(256, 2) void halo_fused(
    const float* __restrict__ x,
    const float* __restrict__ Wq, const float* __restrict__ Wk,
    const float* __restrict__ Wv, const float* __restrict__ Wp,
    const float* __restrict__ bq, const float* __restrict__ bk,
    const float* __restrict__ bv, const float* __restrict__ bp,
    const float* __restrict__ bt,
    ushort_t* __restrict__ Wqkv, ushort_t* __restrict__ Wpb,
    float* __restrict__ bqkv, float* __restrict__ bpb,
    ushort_t* __restrict__ QKV, ushort_t* __restrict__ Ob,
    ushort_t* __restrict__ biasf, float* __restrict__ out)
{
    __shared__ ushort_t smem[24576];   // 48 KB, unioned across phases

    const int bid  = blockIdx.x;
    const int t    = threadIdx.x;
    const int wave = t >> 6;
    const int lane = t & 63;
    const int quad = lane >> 4;
    const int l15  = lane & 15;

    cg::grid_group grid = cg::this_grid();

    // ---------------- phase 0: pack weights/biases + bias fragments --------
    if (bid < 257) {
        int idx = bid * 256 + t;
        if (idx < 16384)       Wqkv[idx] = f2b(Wq[idx]);
        else if (idx < 32768)  Wqkv[idx] = f2b(Wk[idx - 16384]);
        else if (idx < 49152)  Wqkv[idx] = f2b(Wv[idx - 32768]);
        else if (idx < 65536)  Wpb[idx - 49152] = f2b(Wp[idx - 49152]);
        else {
            int e = idx - 65536;                 // 0..255, two elems each
            for (int k = e; k < 512; k += 256) {
                if (k < 128)      bqkv[k] = bq[k];
                else if (k < 256) bqkv[k] = bk[k - 128];
                else if (k < 384) bqkv[k] = bv[k - 256];
                else              bpb[k - 384] = bp[k - 384];
            }
        }
    }
    // bias fragments: [h(4)][kt(64)][qrow(16)][lane(64)] x 4 ushorts;
    // 262144 items over 512 blocks = 2 per thread.
    #pragma unroll
    for (int j = 0; j < 2; ++j) {
        int idx = bid * 512 + j * 256 + t;
        int ln  = idx & 63;
        int qtw = (idx >> 6) & 15;
        int kt  = (idx >> 10) & 63;
        int h   = (idx >> 16) & 3;
        int q     = qtw * 16 + (ln & 15);
        int kbase = kt * 16 + ((ln >> 4) << 2);
        unsigned v[4];
        #pragma unroll
        for (int r = 0; r < 4; ++r) {
            int key = kbase + r;
            int kr = key >> 5, kc = key & 31;
            int bidx = ((q >> 5) + 31 - kr) * 47 + (q & 31) - kc + 23;
            if (bidx < 0) bidx += BTBL;
            v[r] = f2b(bt[bidx * NHEADS + h] * LOG2E);
        }
        uint2 o;
        o.x = v[0] | (v[1] << 16);
        o.y = v[2] | (v[3] << 16);
        *(uint2*)&biasf[(size_t)idx * 4] = o;
    }
    __threadfence();
    grid.sync();

    // ---------------- phase 1: QKV GEMM, 64-row tile per block -------------
    {
        const int m0 = bid * 64;
        #pragma unroll
        for (int i = 0; i < 8; ++i) {
            int s = t + i * 256;
            int row = s >> 5, c4 = s & 31;
            float4 v = *(const float4*)&x[(size_t)(m0 + row) * 128 + c4 * 4];
            uint2 pk;
            pk.x = (unsigned)f2b(v.x) | ((unsigned)f2b(v.y) << 16);
            pk.y = (unsigned)f2b(v.z) | ((unsigned)f2b(v.w) << 16);
            *(uint2*)&smem[row * 136 + c4 * 4] = pk;
        }
        __syncthreads();

        #pragma unroll 1
        for (int nb = 0; nb < 3; ++nb) {
            const float sc = (nb == 0) ? QSCALE : 1.0f;
            floatx4 acc[8];
            #pragma unroll
            for (int nt = 0; nt < 8; ++nt)
                acc[nt] = *(const floatx4*)&bqkv[nb * 128 + nt * 16 + quad * 4];

            #pragma unroll
            for (int kc = 0; kc < 4; ++kc) {
                bf16x8 af = *(const bf16x8*)&smem[(wave * 16 + l15) * 136 + kc * 32 + quad * 8];
                bf16x8 bfr[8];
                #pragma unroll
                for (int nt = 0; nt < 8; ++nt)
                    bfr[nt] = *(const bf16x8*)&Wqkv[(size_t)(nb * 128 + nt * 16 + l15) * 128 + kc * 32 + quad * 8];
                #pragma unroll
                for (int nt = 0; nt < 8; ++nt)
                    acc[nt] = __builtin_amdgcn_mfma_f32_16x16x32_bf16(bfr[nt], af, acc[nt], 0, 0, 0);
            }

            int m = m0 + wave * 16 + l15;
            #pragma unroll
            for (int nt = 0; nt < 8; ++nt) {
                int n = nb * 128 + nt * 16 + quad * 4;
                uint2 pk;
                pk.x = (unsigned)f2b(acc[nt][0] * sc) | ((unsigned)f2b(acc[nt][1] * sc) << 16);
                pk.y = (unsigned)f2b(acc[nt][2] * sc) | ((unsigned)f2b(acc[nt][3] * sc) << 16);
                *(uint2*)&QKV[(size_t)m * 384 + n] = pk;
            }
        }
    }
    __threadfence();
    grid.sync();

    // ---------------- phase 2: halo attention (R8 body, verbatim) ----------
    {
        ushort_t* P_lds  = smem;            // 4*64*64 ushorts = 32 KB
        ushort_t* Vt_lds = smem + 16384;    // 4*32*64 ushorts = 16 KB
        const int swz  = (l15 & 7) << 3;

        const int win  = bid & 127;
        const int head = bid >> 7;
        const int b    = win >> 6;
        const int wh   = (win >> 3) & 7;
        const int ww   = win & 7;

        bf16x8 qf[4];
        int qpix[4];
        #pragma unroll
        for (int qt = 0; qt < 4; ++qt) {
            int q_abs = wave * 64 + qt * 16 + l15;
            int gy = wh * 16 + (q_abs >> 4), gx = ww * 16 + (q_abs & 15);
            int pix = (b * 128 + gy) * 128 + gx;
            qpix[qt] = pix;
            qf[qt] = *(const bf16x8*)(QKV + (size_t)pix * 384 + head * 32 + quad * 8);
        }

        floatx4 Oa[2][4];
        #pragma unroll
        for (int dt = 0; dt < 2; ++dt)
            #pragma unroll
            for (int qt = 0; qt < 4; ++qt)
                Oa[dt][qt] = (floatx4)0.f;
        float l[4] = {0.f, 0.f, 0.f, 0.f};

        ushort_t* Pw  = P_lds  + wave * 64 * PK;
        ushort_t* Vtw = Vt_lds + wave * 32 * PK;

        for (int c = 0; c < 16; ++c) {
            {
                int keyv = c * 64 + lane;
                int ky = reflect_idx(wh * 16 + (keyv >> 5) - 8);
                int kx = reflect_idx(ww * 16 + (keyv & 31) - 8);
                int pixv = (b * 128 + ky) * 128 + kx;
                const int4* vp4 = (const int4*)(QKV + (size_t)pixv * 384 + 256 + head * 32);
                int4 vw0 = vp4[0], vw1 = vp4[1], vw2 = vp4[2], vw3 = vp4[3];
                const ushort_t* vs0 = (const ushort_t*)&vw0;
                const ushort_t* vs1 = (const ushort_t*)&vw1;
                const ushort_t* vs2 = (const ushort_t*)&vw2;
                const ushort_t* vs3 = (const ushort_t*)&vw3;
                #pragma unroll
                for (int d = 0; d < 8; ++d) {
                    int cs = lane ^ (d << 3);
                    Vtw[(d +  0) * PK + cs] = vs0[d];
                    Vtw[(d +  8) * PK + cs] = vs1[d];
                    Vtw[(d + 16) * PK + cs] = vs2[d];
                    Vtw[(d + 24) * PK + cs] = vs3[d];
                }
            }

            bf16x8 kf[4];
            #pragma unroll
            for (int kt = 0; kt < 4; ++kt) {
                int key = c * 64 + kt * 16 + l15;
                int ky = reflect_idx(wh * 16 + (key >> 5) - 8);
                int kx = reflect_idx(ww * 16 + (key & 31) - 8);
                int pixk = (b * 128 + ky) * 128 + kx;
                kf[kt] = *(const bf16x8*)(QKV + (size_t)pixk * 384 + 128 + head * 32 + quad * 8);
            }

            floatx4 S[4][4];
            #pragma unroll
            for (int kt = 0; kt < 4; ++kt) {
                int kt_abs = c * 4 + kt;
                #pragma unroll
                for (int qt = 0; qt < 4; ++qt) {
                    size_t off = ((((size_t)head * 64 + kt_abs) * 16 + (wave * 4 + qt)) * 64 + lane) * 4;
                    uint2 bb = *(const uint2*)(biasf + off);
                    floatx4 s;
                    s[0] = __uint_as_float(bb.x << 16);
                    s[1] = __uint_as_float(bb.x & 0xffff0000u);
                    s[2] = __uint_as_float(bb.y << 16);
                    s[3] = __uint_as_float(bb.y & 0xffff0000u);
                    S[kt][qt] = s;
                }
            }
            #pragma unroll
            for (int kt = 0; kt < 4; ++kt)
                #pragma unroll
                for (int qt = 0; qt < 4; ++qt)
                    S[kt][qt] = __builtin_amdgcn_mfma_f32_16x16x32_bf16(kf[kt], qf[qt], S[kt][qt], 0, 0, 0);

            #pragma unroll
            for (int qt = 0; qt < 4; ++qt) {
                float ls = 0.f;
                #pragma unroll
                for (int kt = 0; kt < 4; ++kt) {
                    #pragma unroll
                    for (int r = 0; r < 4; ++r) {
                        float p = __builtin_amdgcn_exp2f(S[kt][qt][r]);
                        S[kt][qt][r] = p;
                        ls += p;
                    }
                }
                l[qt] += ls;
                #pragma unroll
                for (int kt = 0; kt < 4; ++kt) {
                    uint2 pk;
                    pk.x = __builtin_amdgcn_perm(__float_as_uint(S[kt][qt][1]),
                                                 __float_as_uint(S[kt][qt][0]), 0x07060302u);
                    pk.y = __builtin_amdgcn_perm(__float_as_uint(S[kt][qt][3]),
                                                 __float_as_uint(S[kt][qt][2]), 0x07060302u);
                    *(uint2*)&Pw[(qt * 16 + l15) * PK + ((kt * 16 + quad * 4) ^ swz)] = pk;
                }
            }

            #pragma unroll
            for (int ks = 0; ks < 2; ++ks) {
                bf16x8 vf[2];
                #pragma unroll
                for (int dt = 0; dt < 2; ++dt)
                    vf[dt] = *(const bf16x8*)&Vtw[(dt * 16 + l15) * PK + ((ks * 32 + quad * 8) ^ swz)];
                #pragma unroll
                for (int qt = 0; qt < 4; ++qt) {
                    bf16x8 pf = *(const bf16x8*)&Pw[(qt * 16 + l15) * PK + ((ks * 32 + quad * 8) ^ swz)];
                    #pragma unroll
                    for (int dt = 0; dt < 2; ++dt)
                        Oa[dt][qt] = __builtin_amdgcn_mfma_f32_16x16x32_bf16(vf[dt], pf, Oa[dt][qt], 0, 0, 0);
                }
            }
        }

        #pragma unroll
        for (int qt = 0; qt < 4; ++qt) {
            float lq = l[qt];
            lq += __shfl_xor(lq, 16);
            lq += __shfl_xor(lq, 32);
            float inv = 1.0f / lq;
            #pragma unroll
            for (int dt = 0; dt < 2; ++dt) {
                uint2 pk;
                pk.x = (unsigned)f2b(Oa[dt][qt][0] * inv) | ((unsigned)f2b(Oa[dt][qt][1] * inv) << 16);
                pk.y = (unsigned)f2b(Oa[dt][qt][2] * inv) | ((unsigned)f2b(Oa[dt][qt][3] * inv) << 16);
                *(uint2*)(Ob + (size_t)qpix[qt] * 128 + head * 32 + dt * 16 + quad * 4) = pk;
            }
        }
    }
    __threadfence();
    grid.sync();

    // ---------------- phase 3: proj GEMM, 64-row tile per block ------------
    {
        const int m0 = bid * 64;
        #pragma unroll
        for (int i = 0; i < 4; ++i) {
            int s = t + i * 256;
            int row = s >> 4, c8 = s & 15;
            *(int4*)&smem[row * 136 + c8 * 8] =
                *(const int4*)&Ob[(size_t)(m0 + row) * 128 + c8 * 8];
        }
        __syncthreads();

        floatx4 acc[8];
        #pragma unroll
        for (int nt = 0; nt < 8; ++nt)
            acc[nt] = *(const floatx4*)&bpb[nt * 16 + quad * 4];

        #pragma unroll
        for (int kc = 0; kc < 4; ++kc) {
            bf16x8 af = *(const bf16x8*)&smem[(wave * 16 + l15) * 136 + kc * 32 + quad * 8];
            bf16x8 bfr[8];
            #pragma unroll
            for (int nt = 0; nt < 8; ++nt)
                bfr[nt] = *(const bf16x8*)&Wpb[(size_t)(nt * 16 + l15) * 128 + kc * 32 + quad * 8];
            #pragma unroll
            for (int nt = 0; nt < 8; ++nt)
                acc[nt] = __builtin_amdgcn_mfma_f32_16x16x32_bf16(bfr[nt], af, acc[nt], 0, 0, 0);
        }

        int m = m0 + wave * 16 + l15;
        #pragma unroll
        for (int nt = 0; nt < 8; ++nt) {
            int n = nt * 16 + quad * 4;
            float4 v;
            v.x = acc[nt][0]; v.y = acc[nt][1]; v.z = acc[nt][2]; v.w = acc[nt][3];
            *(float4*)&out[(size_t)m * 128 + n] = v;
        }
    }
}

// ===========================================================================
// Fallback path (proven R9/R10 4-launch pipeline), used only if the
// cooperative launch is rejected by the runtime.
// ===========================================================================
__global__ __launch_bounds__(256) void prep(
    const float* __restrict__ Wq, const float* __restrict__ Wk,
    const float* __restrict__ Wv, const float* __restrict__ Wp,
    const float* __restrict__ bq, const float* __restrict__ bk,
    const float* __restrict__ bv, const float* __restrict__ bp,
    const float* __restrict__ bt,
    ushort_t* __restrict__ Wqkv, ushort_t* __restrict__ Wpb,
    float* __restrict__ bqkv, float* __restrict__ bpb,
    ushort_t* __restrict__ bf)
{
    if (blockIdx.x < 257) {
        int idx = blockIdx.x * 256 + threadIdx.x;
        if (idx < 16384)       Wqkv[idx] = f2b(Wq[idx]);
        else if (idx < 32768)  Wqkv[idx] = f2b(Wk[idx - 16384]);
        else if (idx < 49152)  Wqkv[idx] = f2b(Wv[idx - 32768]);
        else if (idx < 65536)  Wpb[idx - 49152] = f2b(Wp[idx - 49152]);
        else {
            int e = idx - 65536;
            for (int k = e; k < 512; k += 256) {
                if (k < 128)      bqkv[k] = bq[k];
                else if (k < 256) bqkv[k] = bk[k - 128];
                else if (k < 384) bqkv[k] = bv[k - 256];
                else              bpb[k - 384] = bp[k - 384];
            }
        }
    } else {
        int idx  = (blockIdx.x - 257) * 256 + threadIdx.x;
        int lane = idx & 63;
        int qtw  = (idx >> 6) & 15;
        int kt   = (idx >> 10) & 63;
        int h    = (idx >> 16) & 3;
        int q     = qtw * 16 + (lane & 15);
        int kbase = kt * 16 + ((lane >> 4) << 2);
        unsigned v[4];
        #pragma unroll
        for (int r = 0; r < 4; ++r) {
            int key = kbase + r;
            int kr = key >> 5, kc = key & 31;
            int bidx = ((q >> 5) + 31 - kr) * 47 + (q & 31) - kc + 23;
            if (bidx < 0) bidx += BTBL;
            v[r] = f2b(bt[bidx * NHEADS + h] * LOG2E);
        }
        uint2 o;
        o.x = v[0] | (v[1] << 16);
        o.y = v[2] | (v[3] << 16);
        *(uint2*)&bf[(size_t)idx * 4] = o;
    }
}

template <bool IN_BF16, bool OUT_BF16, int NB>
__global__ __launch_bounds__(256) void gemm_mfma(
    const void* __restrict__ Xv, const ushort_t* __restrict__ W,
    const float* __restrict__ bias, void* __restrict__ Yv,
    const int ldy, const float scale0)
{
    __shared__ ushort_t Xs[128 * 136];

    const int t    = threadIdx.x;
    const int w    = t >> 6;
    const int lane = t & 63;
    const int quad = lane >> 4;
    const int l15  = lane & 15;
    const int m0   = blockIdx.x * 128;

    if (IN_BF16) {
        const ushort_t* X = (const ushort_t*)Xv;
        #pragma unroll
        for (int i = 0; i < 8; ++i) {
            int s = t + i * 256;
            int row = s >> 4, c8 = s & 15;
            *(int4*)&Xs[row * 136 + c8 * 8] =
                *(const int4*)&X[(size_t)(m0 + row) * 128 + c8 * 8];
        }
    } else {
        const float* X = (const float*)Xv;
        #pragma unroll
        for (int i = 0; i < 16; ++i) {
            int s = t + i * 256;
            int row = s >> 5, c4 = s & 31;
            float4 v = *(const float4*)&X[(size_t)(m0 + row) * 128 + c4 * 4];
            uint2 pk;
            pk.x = (unsigned)f2b(v.x) | ((unsigned)f2b(v.y) << 16);
            pk.y = (unsigned)f2b(v.z) | ((unsigned)f2b(v.w) << 16);
            *(uint2*)&Xs[row * 136 + c4 * 4] = pk;
        }
    }
    __syncthreads();

    #pragma unroll 1
    for (int nb = 0; nb < NB; ++nb) {
        const float sc = (nb == 0) ? scale0 : 1.0f;

        floatx4 acc[2][8];
        #pragma unroll
        for (int nt = 0; nt < 8; ++nt) {
            floatx4 bv = *(const floatx4*)&bias[nb * 128 + nt * 16 + quad * 4];
            acc[0][nt] = bv;
            acc[1][nt] = bv;
        }

        #pragma unroll
        for (int kc = 0; kc < 4; ++kc) {
            bf16x8 af[2], bfr[8];
            #pragma unroll
            for (int mt = 0; mt < 2; ++mt)
                af[mt] = *(const bf16x8*)&Xs[(w * 32 + mt * 16 + l15) * 136 + kc * 32 + quad * 8];
            #pragma unroll
            for (int nt = 0; nt < 8; ++nt)
                bfr[nt] = *(const bf16x8*)&W[(size_t)(nb * 128 + nt * 16 + l15) * 128 + kc * 32 + quad * 8];
            #pragma unroll
            for (int mt = 0; mt < 2; ++mt)
                #pragma unroll
                for (int nt = 0; nt < 8; ++nt)
                    acc[mt][nt] = __builtin_amdgcn_mfma_f32_16x16x32_bf16(bfr[nt], af[mt], acc[mt][nt], 0, 0, 0);
        }

        #pragma unroll
        for (int mt = 0; mt < 2; ++mt) {
            int m = m0 + w * 32 + mt * 16 + l15;
            #pragma unroll
            for (int nt = 0; nt < 8; ++nt) {
                int n = nb * 128 + nt * 16 + quad * 4;
                if (OUT_BF16) {
                    uint2 pk;
                    pk.x = (unsigned)f2b(acc[mt][nt][0] * sc) |
                           ((unsigned)f2b(acc[mt][nt][1] * sc) << 16);
                    pk.y = (unsigned)f2b(acc[mt][nt][2] * sc) |
                           ((unsigned)f2b(acc[mt][nt][3] * sc) << 16);
                    *(uint2*)&((ushort_t*)Yv)[(size_t)m * ldy + n] = pk;
                } else {
                    float4 v;
                    v.x = acc[mt][nt][0] * sc; v.y = acc[mt][nt][1] * sc;
                    v.z = acc[mt][nt][2] * sc; v.w = acc[mt][nt][3] * sc;
                    *(float4*)&((float*)Yv)[(size_t)m * ldy + n] = v;
                }
            }
        }
    }
}

__global__ __launch_bounds__(256, 2) void halo_attn(
    const ushort_t* __restrict__ QKV,
    const ushort_t* __restrict__ biasf,
    ushort_t* __restrict__ O)
{
    __shared__ ushort_t P_lds[4 * 64 * PK];
    __shared__ ushort_t Vt_lds[4 * 32 * PK];

    const int t    = threadIdx.x;
    const int wave = t >> 6;
    const int lane = t & 63;
    const int quad = lane >> 4;
    const int l15  = lane & 15;
    const int swz  = (l15 & 7) << 3;

    const int win  = blockIdx.x;
    const int head = blockIdx.y;
    const int b    = win >> 6;
    const int wh   = (win >> 3) & 7;
    const int ww   = win & 7;

    bf16x8 qf[4];
    int qpix[4];
    #pragma unroll
    for (int qt = 0; qt < 4; ++qt) {
        int q_abs = wave * 64 + qt * 16 + l15;
        int gy = wh * 16 + (q_abs >> 4), gx = ww * 16 + (q_abs & 15);
        int pix = (b * 128 + gy) * 128 + gx;
        qpix[qt] = pix;
        qf[qt] = *(const bf16x8*)(QKV + (size_t)pix * 384 + head * 32 + quad * 8);
    }

    floatx4 Oa[2][4];
    #pragma unroll
    for (int dt = 0; dt < 2; ++dt)
        #pragma unroll
        for (int qt = 0; qt < 4; ++qt)
            Oa[dt][qt] = (floatx4)0.f;
    float l[4] = {0.f, 0.f, 0.f, 0.f};

    ushort_t* Pw  = P_lds  + wave * 64 * PK;
    ushort_t* Vtw = Vt_lds + wave * 32 * PK;

    for (int c = 0; c < 16; ++c) {
        {
            int keyv = c * 64 + lane;
            int ky = reflect_idx(wh * 16 + (keyv >> 5) - 8);
            int kx = reflect_idx(ww * 16 + (keyv & 31) - 8);
            int pixv = (b * 128 + ky) * 128 + kx;
            const int4* vp4 = (const int4*)(QKV + (size_t)pixv * 384 + 256 + head * 32);
            int4 vw0 = vp4[0], vw1 = vp4[1], vw2 = vp4[2], vw3 = vp4[3];
            const ushort_t* vs0 = (const ushort_t*)&vw0;
            const ushort_t* vs1 = (const ushort_t*)&vw1;
            const ushort_t* vs2 = (const ushort_t*)&vw2;
            const ushort_t* vs3 = (const ushort_t*)&vw3;
            #pragma unroll
            for (int d = 0; d < 8; ++d) {
                int cs = lane ^ (d << 3);
                Vtw[(d +  0) * PK + cs] = vs0[d];
                Vtw[(d +  8) * PK + cs] = vs1[d];
                Vtw[(d + 16) * PK + cs] = vs2[d];
                Vtw[(d + 24) * PK + cs] = vs3[d];
            }
        }

        bf16x8 kf[4];
        #pragma unroll
        for (int kt = 0; kt < 4; ++kt) {
            int key = c * 64 + kt * 16 + l15;
            int ky = reflect_idx(wh * 16 + (key >> 5) - 8);
            int kx = reflect_idx(ww * 16 + (key & 31) - 8);
            int pixk = (b * 128 + ky) * 128 + kx;
            kf[kt] = *(const bf16x8*)(QKV + (size_t)pixk * 384 + 128 + head * 32 + quad * 8);
        }

        floatx4 S[4][4];
        #pragma unroll
        for (int kt = 0; kt < 4; ++kt) {
            int kt_abs = c * 4 + kt;
            #pragma unroll
            for (int qt = 0; qt < 4; ++qt) {
                size_t off = ((((size_t)head * 64 + kt_abs) * 16 + (wave * 4 + qt)) * 64 + lane) * 4;
                uint2 bb = *(const uint2*)(biasf + off);
                floatx4 s;
                s[0] = __uint_as_float(bb.x << 16);
                s[1] = __uint_as_float(bb.x & 0xffff0000u);
                s[2] = __uint_as_float(bb.y << 16);
                s[3] = __uint_as_float(bb.y & 0xffff0000u);
                S[kt][qt] = s;
            }
        }
        #pragma unroll
        for (int kt = 0; kt < 4; ++kt)
            #pragma unroll
            for (int qt = 0; qt < 4; ++qt)
                S[kt][qt] = __builtin_amdgcn_mfma_f32_16x16x32_bf16(kf[kt], qf[qt], S[kt][qt], 0, 0, 0);

        #pragma unroll
        for (int qt = 0; qt < 4; ++qt) {
            float ls = 0.f;
            #pragma unroll
            for (int kt = 0; kt < 4; ++kt) {
                #pragma unroll
                for (int r = 0; r < 4; ++r) {
                    float p = __builtin_amdgcn_exp2f(S[kt][qt][r]);
                    S[kt][qt][r] = p;
                    ls += p;
                }
            }
            l[qt] += ls;
            #pragma unroll
            for (int kt = 0; kt < 4; ++kt) {
                uint2 pk;
                pk.x = __builtin_amdgcn_perm(__float_as_uint(S[kt][qt][1]),
                                             __float_as_uint(S[kt][qt][0]), 0x07060302u);
                pk.y = __builtin_amdgcn_perm(__float_as_uint(S[kt][qt][3]),
                                             __float_as_uint(S[kt][qt][2]), 0x07060302u);
                *(uint2*)&Pw[(qt * 16 + l15) * PK + ((kt * 16 + quad * 4) ^ swz)] = pk;
            }
        }

        #pragma unroll
        for (int ks = 0; ks < 2; ++ks) {
            bf16x8 vf[2];
            #pragma unroll
            for (int dt = 0; dt < 2; ++dt)
                vf[dt] = *(const bf16x8*)&Vtw[(dt * 16 + l15) * PK + ((ks * 32 + quad * 8) ^ swz)];
            #pragma unroll
            for (int qt = 0; qt < 4; ++qt) {
                bf16x8 pf = *(const bf16x8*)&Pw[(qt * 16 + l15) * PK + ((ks * 32 + quad * 8) ^ swz)];
                #pragma unroll
                for (int dt = 0; dt < 2; ++dt)
                    Oa[dt][qt] = __builtin_amdgcn_mfma_f32_16x16x32_bf16(vf[dt], pf, Oa[dt][qt], 0, 0, 0);
            }
        }
    }

    #pragma unroll
    for (int qt = 0; qt < 4; ++qt) {
        float lq = l[qt];
        lq += __shfl_xor(lq, 16);
        lq += __shfl_xor(lq, 32);
        float inv = 1.0f / lq;
        #pragma unroll
        for (int dt = 0; dt < 2; ++dt) {
            uint2 pk;
            pk.x = (unsigned)f2b(Oa[dt][qt][0] * inv) | ((unsigned)f2b(Oa[dt][qt][1] * inv) << 16);
            pk.y = (unsigned)f2b(Oa[dt][qt][2] * inv) | ((unsigned)f2b(Oa[dt][qt][3] * inv) << 16);
            *(uint2*)(O + (size_t)qpix[qt] * 128 + head * 32 + dt * 16 + quad * 4) = pk;
        }
    }
}

// ---------------------------------------------------------------------------
extern "C" void kernel_launch(void* const* d_in, const int* in_sizes, int n_in,
                              void* d_out, int out_size, void* d_ws, size_t ws_size,
                              hipStream_t stream)
{
    const float* x          = (const float*)d_in[0];
    const float* Wq         = (const float*)d_in[1];
    const float* bq         = (const float*)d_in[2];
    const float* Wk         = (const float*)d_in[3];
    const float* bk         = (const float*)d_in[4];
    const float* Wv         = (const float*)d_in[5];
    const float* bv         = (const float*)d_in[6];
    const float* Wp         = (const float*)d_in[7];
    const float* bp         = (const float*)d_in[8];
    const float* bias_table = (const float*)d_in[9];
    float* out = (float*)d_out;

    char* ws = (char*)d_ws;
    ushort_t* Wqkv = (ushort_t*)(ws);                    // 98304 B
    ushort_t* Wpb  = (ushort_t*)(ws + 98304);            // 32768 B
    float*    bqkv = (float*)   (ws + 131072);           // 1536 B
    float*    bpb  = (float*)   (ws + 132608);           // 512 B
    ushort_t* QKV  = (ushort_t*)(ws + 133120);           // 25165824 B
    ushort_t* Ob   = (ushort_t*)(ws + 25298944);         // 8388608 B
    ushort_t* bf   = (ushort_t*)(ws + 33687552);         // 2097152 B (bf16)

    // --- fused single-dispatch cooperative path ---
    const float *x_ = x, *Wq_ = Wq, *Wk_ = Wk, *Wv_ = Wv, *Wp_ = Wp;
    const float *bq_ = bq, *bk_ = bk, *bv_ = bv, *bp_ = bp, *bt_ = bias_table;
    ushort_t *Wqkv_ = Wqkv, *Wpb_ = Wpb, *QKV_ = QKV, *Ob_ = Ob, *bf_ = bf;
    float *bqkv_ = bqkv, *bpb_ = bpb, *out_ = out;
    void* kargs[] = {
        (void*)&x_, (void*)&Wq_, (void*)&Wk_, (void*)&Wv_, (void*)&Wp_,
        (void*)&bq_, (void*)&bk_, (void*)&bv_, (void*)&bp_, (void*)&bt_,
        (void*)&Wqkv_, (void*)&Wpb_, (void*)&bqkv_, (void*)&bpb_,
        (void*)&QKV_, (void*)&Ob_, (void*)&bf_, (void*)&out_ };

    hipError_t err = hipLaunchCooperativeKernel(
        (const void*)halo_fused, dim3(512), dim3(256), kargs, 0u, stream);

    if (err != hipSuccess) {
        (void)hipGetLastError();   // clear sticky error, fall back
        prep<<<dim3(1281), dim3(256), 0, stream>>>(Wq, Wk, Wv, Wp, bq, bk, bv, bp,
                                                   bias_table, Wqkv, Wpb, bqkv, bpb, bf);
        gemm_mfma<false, true, 3><<<dim3(256), dim3(256), 0, stream>>>(
            x, Wqkv, bqkv, QKV, 384, QSCALE);
        halo_attn<<<dim3(128, NHEADS), dim3(256), 0, stream>>>(QKV, bf, Ob);
        gemm_mfma<true, false, 1><<<dim3(256), dim3(256), 0, stream>>>(
            Ob, Wpb, bpb, out, 128, 1.0f);
    }
}

// Round 7
// 158.070 us; speedup vs baseline: 3.2418x; 3.2418x over previous
//
#include <hip/hip_runtime.h>

// HaloAttention. B=2, H=W=128, C=128, NH=4, hd=32, WS=16, HS=8, WSH=32.
// R12: revert R11 coop fusion (grid.sync ~100us each => 415us kernel).
// Back to R9 4-launch structure. Single change vs R9: head-major K/V layout
// (Q[pix][128], K[head][pix][32], V[head][pix][32]) so halo's K/V loads are
// contiguous in pixel order (wave-instr = 1KB dense) instead of stride-768
// gathers touching 16-64 cache lines per instruction. halo math/swizzle
// byte-identical to R8.

typedef unsigned short ushort_t;
typedef __attribute__((ext_vector_type(8))) short bf16x8;
typedef __attribute__((ext_vector_type(4))) float floatx4;

#define NHEADS 4
#define BTBL 2209          // 47*47 bias table rows
#define PK 64              // key stride (bf16) for P/Vt LDS rows (128B, aligned)
#define LOG2E 1.4426950408889634f
#define QSCALE (0.17677669529663687f * LOG2E)   // head_dim^-0.5 * log2(e)

__device__ __forceinline__ int reflect_idx(int p) {
    p = (p < 0) ? -p : p;
    p = (p > 127) ? 254 - p : p;
    return p;
}

// fp32 -> bf16 bits, RNE
__device__ __forceinline__ ushort_t f2b(float x) {
    unsigned u = __float_as_uint(x);
    return (ushort_t)((u + 0x7fffu + ((u >> 16) & 1u)) >> 16);
}

// ---------------------------------------------------------------------------
// Fused prep: blocks [0,257) pack weights/biases; blocks [257,1281) build the
// bf16 bias fragments (pre-scaled by log2e).
__global__ __launch_bounds__(256) void prep(
    const float* __restrict__ Wq, const float* __restrict__ Wk,
    const float* __restrict__ Wv, const float* __restrict__ Wp,
    const float* __restrict__ bq, const float* __restrict__ bk,
    const float* __restrict__ bv, const float* __restrict__ bp,
    const float* __restrict__ bt,
    ushort_t* __restrict__ Wqkv, ushort_t* __restrict__ Wpb,
    float* __restrict__ bqkv, float* __restrict__ bpb,
    ushort_t* __restrict__ bf)
{
    if (blockIdx.x < 257) {
        int idx = blockIdx.x * 256 + threadIdx.x;
        if (idx < 16384)       Wqkv[idx] = f2b(Wq[idx]);
        else if (idx < 32768)  Wqkv[idx] = f2b(Wk[idx - 16384]);
        else if (idx < 49152)  Wqkv[idx] = f2b(Wv[idx - 32768]);
        else if (idx < 65536)  Wpb[idx - 49152] = f2b(Wp[idx - 49152]);
        else {
            int e = idx - 65536;                 // 0..255, two elems each
            for (int k = e; k < 512; k += 256) {
                if (k < 128)      bqkv[k] = bq[k];
                else if (k < 256) bqkv[k] = bk[k - 128];
                else if (k < 384) bqkv[k] = bv[k - 256];
                else              bpb[k - 384] = bp[k - 384];
            }
        }
    } else {
        // bias fragments: [h(4)][kt(64)][qrow(16)][lane(64)] x 4 ushorts.
        int idx  = (blockIdx.x - 257) * 256 + threadIdx.x;  // 0..262143
        int lane = idx & 63;
        int qtw  = (idx >> 6) & 15;
        int kt   = (idx >> 10) & 63;
        int h    = (idx >> 16) & 3;
        int q     = qtw * 16 + (lane & 15);
        int kbase = kt * 16 + ((lane >> 4) << 2);
        unsigned v[4];
        #pragma unroll
        for (int r = 0; r < 4; ++r) {
            int key = kbase + r;
            int kr = key >> 5, kc = key & 31;
            int bidx = ((q >> 5) + 31 - kr) * 47 + (q & 31) - kc + 23;
            if (bidx < 0) bidx += BTBL;
            v[r] = f2b(bt[bidx * NHEADS + h] * LOG2E);
        }
        uint2 o;
        o.x = v[0] | (v[1] << 16);
        o.y = v[2] | (v[3] << 16);
        *(uint2*)&bf[(size_t)idx * 4] = o;
    }
}

// ---------------------------------------------------------------------------
// QKV GEMM: X fp32 [32768][128] -> Q[pix][128] (scaled), K/V head-major
// [head][32768][32]. Block tile 128M; 4 waves each 32M; nb looped internally.
// Swapped-operand mfma (regs span n) -> 8B stores.
__global__ __launch_bounds__(256) void gemm_qkv(
    const float* __restrict__ X, const ushort_t* __restrict__ W,
    const float* __restrict__ bias,
    ushort_t* __restrict__ Qb, ushort_t* __restrict__ Kb,
    ushort_t* __restrict__ Vb)
{
    __shared__ ushort_t Xs[128 * 136];

    const int t    = threadIdx.x;
    const int w    = t >> 6;
    const int lane = t & 63;
    const int quad = lane >> 4;
    const int l15  = lane & 15;
    const int m0   = blockIdx.x * 128;

    #pragma unroll
    for (int i = 0; i < 16; ++i) {
        int s = t + i * 256;
        int row = s >> 5, c4 = s & 31;
        float4 v = *(const float4*)&X[(size_t)(m0 + row) * 128 + c4 * 4];
        uint2 pk;
        pk.x = (unsigned)f2b(v.x) | ((unsigned)f2b(v.y) << 16);
        pk.y = (unsigned)f2b(v.z) | ((unsigned)f2b(v.w) << 16);
        *(uint2*)&Xs[row * 136 + c4 * 4] = pk;
    }
    __syncthreads();

    #pragma unroll 1
    for (int nb = 0; nb < 3; ++nb) {
        const float sc = (nb == 0) ? QSCALE : 1.0f;

        floatx4 acc[2][8];
        #pragma unroll
        for (int nt = 0; nt < 8; ++nt) {
            floatx4 bv = *(const floatx4*)&bias[nb * 128 + nt * 16 + quad * 4];
            acc[0][nt] = bv;
            acc[1][nt] = bv;
        }

        #pragma unroll
        for (int kc = 0; kc < 4; ++kc) {
            bf16x8 af[2], bfr[8];
            #pragma unroll
            for (int mt = 0; mt < 2; ++mt)
                af[mt] = *(const bf16x8*)&Xs[(w * 32 + mt * 16 + l15) * 136 + kc * 32 + quad * 8];
            #pragma unroll
            for (int nt = 0; nt < 8; ++nt)
                bfr[nt] = *(const bf16x8*)&W[(size_t)(nb * 128 + nt * 16 + l15) * 128 + kc * 32 + quad * 8];
            #pragma unroll
            for (int mt = 0; mt < 2; ++mt)
                #pragma unroll
                for (int nt = 0; nt < 8; ++nt)
                    acc[mt][nt] = __builtin_amdgcn_mfma_f32_16x16x32_bf16(bfr[nt], af[mt], acc[mt][nt], 0, 0, 0);
        }

        #pragma unroll
        for (int mt = 0; mt < 2; ++mt) {
            int m = m0 + w * 32 + mt * 16 + l15;
            #pragma unroll
            for (int nt = 0; nt < 8; ++nt) {
                int n = nt * 16 + quad * 4;          // 0..124, within 128 slice
                uint2 pk;
                pk.x = (unsigned)f2b(acc[mt][nt][0] * sc) |
                       ((unsigned)f2b(acc[mt][nt][1] * sc) << 16);
                pk.y = (unsigned)f2b(acc[mt][nt][2] * sc) |
                       ((unsigned)f2b(acc[mt][nt][3] * sc) << 16);
                if (nb == 0) {
                    *(uint2*)&Qb[(size_t)m * 128 + n] = pk;
                } else {
                    // head-major: [head][pix][32]
                    size_t off = (((size_t)(n >> 5) << 15) + m) * 32 + (n & 31);
                    if (nb == 1) *(uint2*)&Kb[off] = pk;
                    else         *(uint2*)&Vb[off] = pk;
                }
            }
        }
    }
}

// ---------------------------------------------------------------------------
// Proj GEMM: Ob bf16 [32768][128] @ Wp^T + bp -> out fp32. (R9 verbatim)
__global__ __launch_bounds__(256) void gemm_proj(
    const ushort_t* __restrict__ X, const ushort_t* __restrict__ W,
    const float* __restrict__ bias, float* __restrict__ out)
{
    __shared__ ushort_t Xs[128 * 136];

    const int t    = threadIdx.x;
    const int w    = t >> 6;
    const int lane = t & 63;
    const int quad = lane >> 4;
    const int l15  = lane & 15;
    const int m0   = blockIdx.x * 128;

    #pragma unroll
    for (int i = 0; i < 8; ++i) {
        int s = t + i * 256;
        int row = s >> 4, c8 = s & 15;
        *(int4*)&Xs[row * 136 + c8 * 8] =
            *(const int4*)&X[(size_t)(m0 + row) * 128 + c8 * 8];
    }
    __syncthreads();

    floatx4 acc[2][8];
    #pragma unroll
    for (int nt = 0; nt < 8; ++nt) {
        floatx4 bv = *(const floatx4*)&bias[nt * 16 + quad * 4];
        acc[0][nt] = bv;
        acc[1][nt] = bv;
    }

    #pragma unroll
    for (int kc = 0; kc < 4; ++kc) {
        bf16x8 af[2], bfr[8];
        #pragma unroll
        for (int mt = 0; mt < 2; ++mt)
            af[mt] = *(const bf16x8*)&Xs[(w * 32 + mt * 16 + l15) * 136 + kc * 32 + quad * 8];
        #pragma unroll
        for (int nt = 0; nt < 8; ++nt)
            bfr[nt] = *(const bf16x8*)&W[(size_t)(nt * 16 + l15) * 128 + kc * 32 + quad * 8];
        #pragma unroll
        for (int mt = 0; mt < 2; ++mt)
            #pragma unroll
            for (int nt = 0; nt < 8; ++nt)
                acc[mt][nt] = __builtin_amdgcn_mfma_f32_16x16x32_bf16(bfr[nt], af[mt], acc[mt][nt], 0, 0, 0);
    }

    #pragma unroll
    for (int mt = 0; mt < 2; ++mt) {
        int m = m0 + w * 32 + mt * 16 + l15;
        #pragma unroll
        for (int nt = 0; nt < 8; ++nt) {
            int n = nt * 16 + quad * 4;
            float4 v;
            v.x = acc[mt][nt][0]; v.y = acc[mt][nt][1];
            v.z = acc[mt][nt][2]; v.w = acc[mt][nt][3];
            *(float4*)&out[(size_t)m * 128 + n] = v;
        }
    }
}

// ---------------------------------------------------------------------------
// One block per (window, head); 4 independent waves, each owns 64 queries.
// R8 body; only the Q/K/V load addressing changed to the head-major layout.
__global__ __launch_bounds__(256, 2) void halo_attn(
    const ushort_t* __restrict__ Qb,   // [32768][128] bf16 (pre-scaled)
    const ushort_t* __restrict__ Kb,   // [4][32768][32] bf16
    const ushort_t* __restrict__ Vb,   // [4][32768][32] bf16
    const ushort_t* __restrict__ biasf,
    ushort_t* __restrict__ O)          // [32768][128] bf16
{
    __shared__ ushort_t P_lds[4 * 64 * PK];
    __shared__ ushort_t Vt_lds[4 * 32 * PK];

    const int t    = threadIdx.x;
    const int wave = t >> 6;
    const int lane = t & 63;
    const int quad = lane >> 4;
    const int l15  = lane & 15;
    const int swz  = (l15 & 7) << 3;   // row-derived XOR (row&7 == l15&7)

    const int win  = blockIdx.x;
    const int head = blockIdx.y;
    const int b    = win >> 6;
    const int wh   = (win >> 3) & 7;
    const int ww   = win & 7;
    const size_t hbase = (size_t)head << 15;    // head * 32768

    bf16x8 qf[4];
    int qpix[4];
    #pragma unroll
    for (int qt = 0; qt < 4; ++qt) {
        int q_abs = wave * 64 + qt * 16 + l15;
        int gy = wh * 16 + (q_abs >> 4), gx = ww * 16 + (q_abs & 15);
        int pix = (b * 128 + gy) * 128 + gx;
        qpix[qt] = pix;
        qf[qt] = *(const bf16x8*)(Qb + (size_t)pix * 128 + head * 32 + quad * 8);
    }

    floatx4 Oa[2][4];
    #pragma unroll
    for (int dt = 0; dt < 2; ++dt)
        #pragma unroll
        for (int qt = 0; qt < 4; ++qt)
            Oa[dt][qt] = (floatx4)0.f;
    float l[4] = {0.f, 0.f, 0.f, 0.f};

    ushort_t* Pw  = P_lds  + wave * 64 * PK;
    ushort_t* Vtw = Vt_lds + wave * 32 * PK;

    for (int c = 0; c < 16; ++c) {
        // ---- V chunk -> LDS transposed (per-wave): lane owns one key ----
        {
            int keyv = c * 64 + lane;
            int ky = reflect_idx(wh * 16 + (keyv >> 5) - 8);
            int kx = reflect_idx(ww * 16 + (keyv & 31) - 8);
            int pixv = (b * 128 + ky) * 128 + kx;
            const int4* vp4 = (const int4*)(Vb + ((hbase + pixv) << 5));
            int4 vw0 = vp4[0], vw1 = vp4[1], vw2 = vp4[2], vw3 = vp4[3];
            const ushort_t* vs0 = (const ushort_t*)&vw0;
            const ushort_t* vs1 = (const ushort_t*)&vw1;
            const ushort_t* vs2 = (const ushort_t*)&vw2;
            const ushort_t* vs3 = (const ushort_t*)&vw3;
            #pragma unroll
            for (int d = 0; d < 8; ++d) {
                int cs = lane ^ (d << 3);    // rows d,d+8,d+16,d+24: row&7 == d
                Vtw[(d +  0) * PK + cs] = vs0[d];
                Vtw[(d +  8) * PK + cs] = vs1[d];
                Vtw[(d + 16) * PK + cs] = vs2[d];
                Vtw[(d + 24) * PK + cs] = vs3[d];
            }
        }

        // ---- K A-fragments (coalesced: 16 consecutive pixels x 64B) ----
        bf16x8 kf[4];
        #pragma unroll
        for (int kt = 0; kt < 4; ++kt) {
            int key = c * 64 + kt * 16 + l15;
            int ky = reflect_idx(wh * 16 + (key >> 5) - 8);
            int kx = reflect_idx(ww * 16 + (key & 31) - 8);
            int pixk = (b * 128 + ky) * 128 + kx;
            kf[kt] = *(const bf16x8*)(Kb + ((hbase + pixk) << 5) + quad * 8);
        }

        // ---- S^T tiles: acc init = bias fragment (bf16 unpack), then mfma ----
        floatx4 S[4][4];
        #pragma unroll
        for (int kt = 0; kt < 4; ++kt) {
            int kt_abs = c * 4 + kt;
            #pragma unroll
            for (int qt = 0; qt < 4; ++qt) {
                size_t off = ((((size_t)head * 64 + kt_abs) * 16 + (wave * 4 + qt)) * 64 + lane) * 4;
                uint2 bb = *(const uint2*)(biasf + off);
                floatx4 s;
                s[0] = __uint_as_float(bb.x << 16);
                s[1] = __uint_as_float(bb.x & 0xffff0000u);
                s[2] = __uint_as_float(bb.y << 16);
                s[3] = __uint_as_float(bb.y & 0xffff0000u);
                S[kt][qt] = s;
            }
        }
        #pragma unroll
        for (int kt = 0; kt < 4; ++kt)
            #pragma unroll
            for (int qt = 0; qt < 4; ++qt)
                S[kt][qt] = __builtin_amdgcn_mfma_f32_16x16x32_bf16(kf[kt], qf[qt], S[kt][qt], 0, 0, 0);

        // ---- exp2 + partial l + pack P (no max subtraction, no rescale) ----
        #pragma unroll
        for (int qt = 0; qt < 4; ++qt) {
            float ls = 0.f;
            #pragma unroll
            for (int kt = 0; kt < 4; ++kt) {
                #pragma unroll
                for (int r = 0; r < 4; ++r) {
                    float p = __builtin_amdgcn_exp2f(S[kt][qt][r]);
                    S[kt][qt][r] = p;
                    ls += p;
                }
            }
            l[qt] += ls;
            #pragma unroll
            for (int kt = 0; kt < 4; ++kt) {
                uint2 pk;
                pk.x = __builtin_amdgcn_perm(__float_as_uint(S[kt][qt][1]),
                                             __float_as_uint(S[kt][qt][0]), 0x07060302u);
                pk.y = __builtin_amdgcn_perm(__float_as_uint(S[kt][qt][3]),
                                             __float_as_uint(S[kt][qt][2]), 0x07060302u);
                *(uint2*)&Pw[(qt * 16 + l15) * PK + ((kt * 16 + quad * 4) ^ swz)] = pk;
            }
        }

        // ---- PV: O^T += V^T . P^T ----
        #pragma unroll
        for (int ks = 0; ks < 2; ++ks) {
            bf16x8 vf[2];
            #pragma unroll
            for (int dt = 0; dt < 2; ++dt)
                vf[dt] = *(const bf16x8*)&Vtw[(dt * 16 + l15) * PK + ((ks * 32 + quad * 8) ^ swz)];
            #pragma unroll
            for (int qt = 0; qt < 4; ++qt) {
                bf16x8 pf = *(const bf16x8*)&Pw[(qt * 16 + l15) * PK + ((ks * 32 + quad * 8) ^ swz)];
                #pragma unroll
                for (int dt = 0; dt < 2; ++dt)
                    Oa[dt][qt] = __builtin_amdgcn_mfma_f32_16x16x32_bf16(vf[dt], pf, Oa[dt][qt], 0, 0, 0);
            }
        }
    }

    // ---- epilogue: reduce l across quads, normalize, bf16 store ----
    #pragma unroll
    for (int qt = 0; qt < 4; ++qt) {
        float lq = l[qt];
        lq += __shfl_xor(lq, 16);
        lq += __shfl_xor(lq, 32);
        float inv = 1.0f / lq;
        #pragma unroll
        for (int dt = 0; dt < 2; ++dt) {
            uint2 pk;
            pk.x = (unsigned)f2b(Oa[dt][qt][0] * inv) | ((unsigned)f2b(Oa[dt][qt][1] * inv) << 16);
            pk.y = (unsigned)f2b(Oa[dt][qt][2] * inv) | ((unsigned)f2b(Oa[dt][qt][3] * inv) << 16);
            *(uint2*)(O + (size_t)qpix[qt] * 128 + head * 32 + dt * 16 + quad * 4) = pk;
        }
    }
}

// ---------------------------------------------------------------------------
extern "C" void kernel_launch(void* const* d_in, const int* in_sizes, int n_in,
                              void* d_out, int out_size, void* d_ws, size_t ws_size,
                              hipStream_t stream)
{
    const float* x          = (const float*)d_in[0];
    const float* Wq         = (const float*)d_in[1];
    const float* bq         = (const float*)d_in[2];
    const float* Wk         = (const float*)d_in[3];
    const float* bk         = (const float*)d_in[4];
    const float* Wv         = (const float*)d_in[5];
    const float* bv         = (const float*)d_in[6];
    const float* Wp         = (const float*)d_in[7];
    const float* bp         = (const float*)d_in[8];
    const float* bias_table = (const float*)d_in[9];
    float* out = (float*)d_out;

    char* ws = (char*)d_ws;
    ushort_t* Wqkv = (ushort_t*)(ws);                    // 98304 B
    ushort_t* Wpb  = (ushort_t*)(ws + 98304);            // 32768 B
    float*    bqkv = (float*)   (ws + 131072);           // 1536 B
    float*    bpb  = (float*)   (ws + 132608);           // 512 B
    ushort_t* Qb   = (ushort_t*)(ws + 133120);           // 8388608 B
    ushort_t* Kb   = (ushort_t*)(ws + 8521728);          // 8388608 B
    ushort_t* Vb   = (ushort_t*)(ws + 16910336);         // 8388608 B
    ushort_t* Ob   = (ushort_t*)(ws + 25298944);         // 8388608 B
    ushort_t* bf   = (ushort_t*)(ws + 33687552);         // 2097152 B (bf16)

    prep<<<dim3(1281), dim3(256), 0, stream>>>(Wq, Wk, Wv, Wp, bq, bk, bv, bp,
                                               bias_table, Wqkv, Wpb, bqkv, bpb, bf);
    gemm_qkv<<<dim3(256), dim3(256), 0, stream>>>(x, Wqkv, bqkv, Qb, Kb, Vb);
    halo_attn<<<dim3(128, NHEADS), dim3(256), 0, stream>>>(Qb, Kb, Vb, bf, Ob);
    gemm_proj<<<dim3(256), dim3(256), 0, stream>>>(Ob, Wpb, bpb, out);
}